// Round 6
// baseline (633.914 us; speedup 1.0000x reference)
//
#include <hip/hip_runtime.h>

// LinearAttentionBlock: H(4,8192,1024) f32
// qkv = H@Wqkv^T + b; q,k = elu+1; per (b,h): kv = K^T V, k1 = sum k
// out = (q@kv)/(q.k1); scrambled reshape; @Wproj^T + b; LN; + residual
//
// R5: GEMM2 -> gemm128 experiment (128^2 tile, 64KB LDS, 2 blocks/CU,
// counted vmcnt(8) with full-tile prefetch window, swizzled reads).
// kv_reduce merged into apply_attn. GEMM1 stays on verified gemm256.

typedef __attribute__((ext_vector_type(4))) float f32x4;
typedef __attribute__((ext_vector_type(8))) short bf16x8;

__device__ __forceinline__ unsigned short f2b(float f) {
    unsigned u = __float_as_uint(f);
    u = (u + 0x7FFFu + ((u >> 16) & 1u)) >> 16;  // RNE
    return (unsigned short)u;
}
__device__ __forceinline__ float b2f(unsigned short h) {
    return __uint_as_float(((unsigned)h) << 16);
}

// async global->LDS, 16B per lane; LDS dest = wave-uniform base + lane*16.
__device__ __forceinline__ void glds16(const void* gp, void* lp) {
    __builtin_amdgcn_global_load_lds(
        (__attribute__((address_space(1))) void*)(unsigned long long)gp,
        (__attribute__((address_space(3))) void*)(unsigned int)(unsigned long long)lp,
        16, 0, 0);
}

// ---------------- fp32 -> bf16 conversion, all 3 inputs in one launch -----
__global__ __launch_bounds__(256) void cvt_all(const float* __restrict__ H,
                                               const float* __restrict__ Wq,
                                               const float* __restrict__ Wp,
                                               unsigned short* __restrict__ hbf,
                                               unsigned short* __restrict__ wqb,
                                               unsigned short* __restrict__ wpb) {
    const int blk = blockIdx.x;
    const float* src; unsigned short* dst; long n4; int b0, nb;
    if (blk < 1792)      { src = H;  dst = hbf; n4 = 8388608; b0 = 0;    nb = 1792; }
    else if (blk < 1920) { src = Wq; dst = wqb; n4 = 786432;  b0 = 1792; nb = 128; }
    else                 { src = Wp; dst = wpb; n4 = 262144;  b0 = 1920; nb = 64; }
    long i = (long)(blk - b0) * 256 + threadIdx.x;
    const long stride = (long)nb * 256;
    for (; i < n4; i += stride) {
        float4 v = ((const float4*)src)[i];
        ushort4 o;
        o.x = f2b(v.x); o.y = f2b(v.y); o.z = f2b(v.z); o.w = f2b(v.w);
        ((ushort4*)dst)[i] = o;
    }
}

// ---------------- bf16 MFMA GEMM, C = A @ B^T (+bias), 256^2 8-wave -------
// (verified R3/R4 structure: 813 TF @ K=1024; unchanged)
template<int MODE>
__global__ __launch_bounds__(512) void gemm256(const unsigned short* __restrict__ A,
                                               const unsigned short* __restrict__ B,
                                               const float* __restrict__ bias,
                                               void* __restrict__ Cout,
                                               int mb, int N, int K) {
    __shared__ unsigned short lds[2][2][256][64];  // 128 KiB
    const int tid = threadIdx.x;
    const int wid = tid >> 6, lane = tid & 63;
    const int wr = wid >> 2, wc = wid & 3;       // 2M x 4N waves
    const int lr = lane & 15, lq = lane >> 4;
    const int cpx = (int)gridDim.x >> 3;
    const int L = ((int)blockIdx.x & 7) * cpx + ((int)blockIdx.x >> 3);
    const int bm = L % mb, bn = L / mb;          // bn-major: chunk shares B-panel
    const size_t aRow0 = (size_t)bm * 256, bRow0 = (size_t)bn * 256;

    const int sr8 = lane >> 3;
    const int ssw = ((lane & 7) ^ sr8) * 8;      // pre-swizzled source col
    const unsigned short* aG = A + (aRow0 + (size_t)(wid * 8 + sr8)) * K + ssw;
    const unsigned short* bG = B + (bRow0 + (size_t)(wid * 8 + sr8)) * K + ssw;

    f32x4 acc[8][4] = {};
    const char* base = (const char*)&lds[0][0][0][0];

    auto stage = [&](int buf, int k0) {
#pragma unroll
        for (int j = 0; j < 8; ++j) {
            const unsigned short* g = (j < 4 ? aG : bG) + (size_t)(j & 3) * 64 * K + k0;
            glds16(g, &lds[buf][j >> 2][(j & 3) * 64 + wid * 8][0]);
        }
    };
    auto ldA = [&](int cur, int mi, int ks) {
        int row = wr * 128 + mi * 16 + lr;
        int off = (cur * 2 + 0) * 32768 + row * 128 + ((((ks << 2) | lq) ^ (row & 7)) << 4);
        return *(const bf16x8*)(base + off);
    };
    auto ldB = [&](int cur, int ni, int ks) {
        int row = wc * 64 + ni * 16 + lr;
        int off = (cur * 2 + 1) * 32768 + row * 128 + ((((ks << 2) | lq) ^ (row & 7)) << 4);
        return *(const bf16x8*)(base + off);
    };

    const int nt = K >> 6;
    stage(0, 0);
    asm volatile("s_waitcnt vmcnt(0)" ::: "memory");
    __builtin_amdgcn_s_barrier();

    bf16x8 af[4][2], bfr[4][2];
    for (int t = 0; t < nt; ++t) {
        const int cur = t & 1;
        // ---- phase 0: read A-half(wr) mi0-3 + B ni0-1; stage t+1; MFMA Q(0,0)
#pragma unroll
        for (int mi = 0; mi < 4; ++mi) {
            af[mi][0] = ldA(cur, mi, 0); af[mi][1] = ldA(cur, mi, 1);
        }
#pragma unroll
        for (int ni = 0; ni < 2; ++ni) {
            bfr[ni][0] = ldB(cur, ni, 0); bfr[ni][1] = ldB(cur, ni, 1);
        }
        if (t + 1 < nt) stage(cur ^ 1, (t + 1) << 6);
        __builtin_amdgcn_s_barrier();
        __builtin_amdgcn_s_setprio(1);
#pragma unroll
        for (int mi = 0; mi < 4; ++mi)
#pragma unroll
            for (int ni = 0; ni < 2; ++ni)
#pragma unroll
                for (int ks = 0; ks < 2; ++ks)
                    acc[mi][ni] = __builtin_amdgcn_mfma_f32_16x16x32_bf16(
                        af[mi][ks], bfr[ni][ks], acc[mi][ni], 0, 0, 0);
        __builtin_amdgcn_s_setprio(0);
        __builtin_amdgcn_s_barrier();
        // ---- phase 1: read B ni2-3; MFMA Q(0,1)
#pragma unroll
        for (int ni = 2; ni < 4; ++ni) {
            bfr[ni][0] = ldB(cur, ni, 0); bfr[ni][1] = ldB(cur, ni, 1);
        }
        __builtin_amdgcn_s_barrier();
        __builtin_amdgcn_s_setprio(1);
#pragma unroll
        for (int mi = 0; mi < 4; ++mi)
#pragma unroll
            for (int ni = 2; ni < 4; ++ni)
#pragma unroll
                for (int ks = 0; ks < 2; ++ks)
                    acc[mi][ni] = __builtin_amdgcn_mfma_f32_16x16x32_bf16(
                        af[mi][ks], bfr[ni][ks], acc[mi][ni], 0, 0, 0);
        __builtin_amdgcn_s_setprio(0);
        __builtin_amdgcn_s_barrier();
        // ---- phase 2: read A-half mi4-7 (reuse af regs); MFMA Q(1,1)
#pragma unroll
        for (int mi = 0; mi < 4; ++mi) {
            af[mi][0] = ldA(cur, mi + 4, 0); af[mi][1] = ldA(cur, mi + 4, 1);
        }
        __builtin_amdgcn_s_barrier();
        __builtin_amdgcn_s_setprio(1);
#pragma unroll
        for (int mi = 0; mi < 4; ++mi)
#pragma unroll
            for (int ni = 2; ni < 4; ++ni)
#pragma unroll
                for (int ks = 0; ks < 2; ++ks)
                    acc[mi + 4][ni] = __builtin_amdgcn_mfma_f32_16x16x32_bf16(
                        af[mi][ks], bfr[ni][ks], acc[mi + 4][ni], 0, 0, 0);
        __builtin_amdgcn_s_setprio(0);
        __builtin_amdgcn_s_barrier();
        // ---- phase 3: MFMA Q(1,0) (no reads)
        __builtin_amdgcn_s_setprio(1);
#pragma unroll
        for (int mi = 0; mi < 4; ++mi)
#pragma unroll
            for (int ni = 0; ni < 2; ++ni)
#pragma unroll
                for (int ks = 0; ks < 2; ++ks)
                    acc[mi + 4][ni] = __builtin_amdgcn_mfma_f32_16x16x32_bf16(
                        af[mi][ks], bfr[ni][ks], acc[mi + 4][ni], 0, 0, 0);
        __builtin_amdgcn_s_setprio(0);
        // ---- tile boundary: next buffer landed; all reads of cur done
        asm volatile("s_waitcnt vmcnt(0)" ::: "memory");
        __builtin_amdgcn_s_barrier();
        __builtin_amdgcn_sched_barrier(0);
    }
    // epilogue: C/D layout col=lane&15, row=(lane>>4)*4+reg
#pragma unroll
    for (int mi = 0; mi < 8; ++mi) {
#pragma unroll
        for (int ni = 0; ni < 4; ++ni) {
            int col = (int)bRow0 + wc * 64 + ni * 16 + lr;
            float bv = bias[col];
#pragma unroll
            for (int r = 0; r < 4; ++r) {
                size_t row = aRow0 + wr * 128 + mi * 16 + lq * 4 + r;
                float v = acc[mi][ni][r] + bv;
                if (MODE == 0) {
                    if (col < 2048) v = (v > 0.f) ? (v + 1.f) : __expf(v);  // elu+1
                }
                ((unsigned short*)Cout)[row * (size_t)N + col] = f2b(v);
            }
        }
    }
}

// ---------------- bf16 MFMA GEMM, 128^2 tile, 2 blocks/CU, counted vmcnt --
// m97-style 2-barrier loop + R3 swizzle. stage(t+1) issued at top of tile t,
// waited via vmcnt(8) at top of tile t+1 -> full-tile prefetch window.
template<int MODE>
__global__ __launch_bounds__(256, 2) void gemm128(const unsigned short* __restrict__ A,
                                                  const unsigned short* __restrict__ B,
                                                  const float* __restrict__ bias,
                                                  void* __restrict__ Cout,
                                                  int mb, int N, int K) {
    __shared__ unsigned short lds[2][2][128][64];  // 64 KiB -> 2 blocks/CU
    const int tid = threadIdx.x;
    const int wave = tid >> 6, lane = tid & 63;
    const int wr = wave >> 1, wc = wave & 1;
    const int lr = lane & 15, lq = lane >> 4;
    const int cpx = (int)gridDim.x >> 3;
    const int L = ((int)blockIdx.x & 7) * cpx + ((int)blockIdx.x >> 3);
    const int bm = L % mb, bn = L / mb;
    const size_t aRow0 = (size_t)bm * 128, bRow0 = (size_t)bn * 128;

    const int sr8 = lane >> 3;
    const int ssw = ((lane & 7) ^ sr8) * 8;
    const unsigned short* aG = A + (aRow0 + (size_t)(wave * 32 + sr8)) * K + ssw;
    const unsigned short* bG = B + (bRow0 + (size_t)(wave * 32 + sr8)) * K + ssw;

    f32x4 acc[4][4] = {};
    const char* base = (const char*)&lds[0][0][0][0];

    auto stage = [&](int buf, int k0) {
#pragma unroll
        for (int i = 0; i < 4; ++i) {
            glds16(aG + (size_t)i * 8 * K + k0, &lds[buf][0][wave * 32 + i * 8][0]);
            glds16(bG + (size_t)i * 8 * K + k0, &lds[buf][1][wave * 32 + i * 8][0]);
        }
    };

    const int nt = K >> 6;
    stage(0, 0);
    for (int t = 0; t < nt; ++t) {
        const int cur = t & 1;
        if (t + 1 < nt) {
            stage(cur ^ 1, (t + 1) << 6);   // buf cur^1 free since end of t-1
            asm volatile("s_waitcnt vmcnt(8)" ::: "memory");  // stage(t) landed
        } else {
            asm volatile("s_waitcnt vmcnt(0)" ::: "memory");
        }
        __builtin_amdgcn_s_barrier();
        bf16x8 af[4][2], bfr[4][2];
#pragma unroll
        for (int mi = 0; mi < 4; ++mi)
#pragma unroll
            for (int ks = 0; ks < 2; ++ks) {
                int row = wr * 64 + mi * 16 + lr;
                af[mi][ks] = *(const bf16x8*)(base + (cur * 2 + 0) * 16384 + row * 128
                                              + ((((ks << 2) | lq) ^ (row & 7)) << 4));
            }
#pragma unroll
        for (int ni = 0; ni < 4; ++ni)
#pragma unroll
            for (int ks = 0; ks < 2; ++ks) {
                int row = wc * 64 + ni * 16 + lr;
                bfr[ni][ks] = *(const bf16x8*)(base + (cur * 2 + 1) * 16384 + row * 128
                                               + ((((ks << 2) | lq) ^ (row & 7)) << 4));
            }
#pragma unroll
        for (int ks = 0; ks < 2; ++ks)
#pragma unroll
            for (int mi = 0; mi < 4; ++mi)
#pragma unroll
                for (int ni = 0; ni < 4; ++ni)
                    acc[mi][ni] = __builtin_amdgcn_mfma_f32_16x16x32_bf16(
                        af[mi][ks], bfr[ni][ks], acc[mi][ni], 0, 0, 0);
        __builtin_amdgcn_s_barrier();  // all reads of cur done before t+1 stages it
    }
    // epilogue
#pragma unroll
    for (int mi = 0; mi < 4; ++mi) {
#pragma unroll
        for (int ni = 0; ni < 4; ++ni) {
            int col = (int)bRow0 + wc * 64 + ni * 16 + lr;
            float bv = bias[col];
#pragma unroll
            for (int r = 0; r < 4; ++r) {
                size_t row = aRow0 + wr * 64 + mi * 16 + lq * 4 + r;
                float v = acc[mi][ni][r] + bv;
                if (MODE == 0) {
                    if (col < 2048) v = (v > 0.f) ? (v + 1.f) : __expf(v);
                }
                ((unsigned short*)Cout)[row * (size_t)N + col] = f2b(v);
            }
        }
    }
}

// ---------------- kv split-K partials: per (b,h,chunk of 1024 rows) -------
// part[(bh*8+chunk)] = [64x64 kv | 64 k1]  (4160 floats)
__global__ __launch_bounds__(256) void kv_partial(const unsigned short* __restrict__ qkv,
                                                  float* __restrict__ part) {
    const int bh = blockIdx.x, chunk = blockIdx.y;
    const int b = bh >> 4, h = bh & 15;
    __shared__ unsigned short kb[16][64];
    __shared__ unsigned short vb[16][64];
    const int tid = threadIdx.x;
    const int d0 = (tid >> 4) * 4, v0 = (tid & 15) * 4;
    float acc[4][4] = {};
    float k1a[4] = {0.f, 0.f, 0.f, 0.f};
    const size_t base = ((size_t)b * 8192 + (size_t)chunk * 1024) * 3072;
    const int nn = tid >> 4;          // staged row 0..15
    const int which = (tid >> 3) & 1; // 0: k, 1: v
    const int cg = tid & 7;           // 8-elem group
    const size_t loff = base + (size_t)nn * 3072 + (which ? 2048 : 1024) + h * 64 + cg * 8;

    for (int n0 = 0; n0 < 1024; n0 += 16) {
        uint4 val = *(const uint4*)(qkv + loff + (size_t)n0 * 3072);
        if (which) *(uint4*)(&vb[nn][cg * 8]) = val;
        else       *(uint4*)(&kb[nn][cg * 8]) = val;
        __syncthreads();
#pragma unroll 4
        for (int j = 0; j < 16; ++j) {
            ushort4 ku = *(const ushort4*)(&kb[j][d0]);
            ushort4 vu = *(const ushort4*)(&vb[j][v0]);
            float kd[4] = {b2f(ku.x), b2f(ku.y), b2f(ku.z), b2f(ku.w)};
            float vd[4] = {b2f(vu.x), b2f(vu.y), b2f(vu.z), b2f(vu.w)};
#pragma unroll
            for (int i = 0; i < 4; ++i)
#pragma unroll
                for (int jj = 0; jj < 4; ++jj)
                    acc[i][jj] += kd[i] * vd[jj];
            if ((tid & 15) == 0)
#pragma unroll
                for (int i = 0; i < 4; ++i) k1a[i] += kd[i];
        }
        __syncthreads();
    }
    float* dst = part + ((size_t)bh * 8 + chunk) * 4160;
#pragma unroll
    for (int i = 0; i < 4; ++i)
#pragma unroll
        for (int jj = 0; jj < 4; ++jj)
            dst[(d0 + i) * 64 + v0 + jj] = acc[i][jj];
    if ((tid & 15) == 0)
#pragma unroll
        for (int i = 0; i < 4; ++i) dst[4096 + d0 + i] = k1a[i];
}

// ---------------- apply: reduce partials + out=(q@kv)/max(q.k1,1e-6) ------
// block: 64 n-rows; thread t: row r=t>>2, col quarter qt=t&3 (16 outputs)
__global__ __launch_bounds__(256) void apply_attn(const unsigned short* __restrict__ qkv,
                                                  const float* __restrict__ part,
                                                  unsigned short* __restrict__ att) {
    const int nblk = blockIdx.x;
    const int bh = blockIdx.y;
    const int b = bh >> 4, h = bh & 15;
    __shared__ float kvs[64][64];
    __shared__ float k1s[64];
    const float* src = part + (size_t)bh * 8 * 4160;
    for (int i = threadIdx.x; i < 4096; i += 256) {
        float s = 0.f;
#pragma unroll
        for (int c = 0; c < 8; ++c) s += src[c * 4160 + i];
        kvs[i >> 6][i & 63] = s;
    }
    if (threadIdx.x < 64) {
        float s = 0.f;
#pragma unroll
        for (int c = 0; c < 8; ++c) s += src[c * 4160 + 4096 + threadIdx.x];
        k1s[threadIdx.x] = s;
    }
    __syncthreads();
    const int t = threadIdx.x;
    const int r = t >> 2, qt = t & 3;
    const int n = nblk * 64 + r;
    const unsigned short* qrow = qkv + ((size_t)b * 8192 + n) * 3072 + h * 64;
    float acc[16] = {};
    float qk1 = 0.f;
    for (int dc = 0; dc < 64; dc += 8) {
        uint4 qu = *(const uint4*)(qrow + dc);
        unsigned qw[4] = {qu.x, qu.y, qu.z, qu.w};
#pragma unroll
        for (int jj = 0; jj < 8; ++jj) {
            float qd = (jj & 1) ? __uint_as_float(qw[jj >> 1] & 0xFFFF0000u)
                                : __uint_as_float(qw[jj >> 1] << 16);
            int d = dc + jj;
            qk1 += qd * k1s[d];
            const float4* kr = (const float4*)(&kvs[d][qt * 16]);  // 4-addr broadcast
            float4 c0 = kr[0], c1 = kr[1], c2 = kr[2], c3 = kr[3];
            acc[0]  += qd * c0.x; acc[1]  += qd * c0.y; acc[2]  += qd * c0.z; acc[3]  += qd * c0.w;
            acc[4]  += qd * c1.x; acc[5]  += qd * c1.y; acc[6]  += qd * c1.z; acc[7]  += qd * c1.w;
            acc[8]  += qd * c2.x; acc[9]  += qd * c2.y; acc[10] += qd * c2.z; acc[11] += qd * c2.w;
            acc[12] += qd * c3.x; acc[13] += qd * c3.y; acc[14] += qd * c3.z; acc[15] += qd * c3.w;
        }
    }
    float rinv = 1.f / fmaxf(qk1, 1e-6f);
    union { unsigned short us[16]; uint4 u4[2]; } ob;
#pragma unroll
    for (int j = 0; j < 16; ++j) ob.us[j] = f2b(acc[j] * rinv);
    // bug-faithful reshape: (h,n,dd) -> row h*512 + n/16, col (n%16)*64 + dd
    unsigned short* dst = att + (((size_t)b * 8192) + h * 512 + (n >> 4)) * 1024
                              + (n & 15) * 64 + qt * 16;
    *(uint4*)dst = ob.u4[0];
    *(uint4*)(dst + 8) = ob.u4[1];
}

// ---------------- LayerNorm + residual, 1 wave per row, barrier-free ------
__global__ __launch_bounds__(256) void ln_residual(const unsigned short* __restrict__ X,
                                                   const float* __restrict__ H,
                                                   const float* __restrict__ gamma,
                                                   const float* __restrict__ beta,
                                                   float* __restrict__ out,
                                                   int nrows) {
    const int lane = threadIdx.x & 63;
    int row = blockIdx.x * 4 + (threadIdx.x >> 6);
    const int rstride = gridDim.x * 4;
    for (; row < nrows; row += rstride) {
        const unsigned short* x = X + (size_t)row * 1024;
        float v[16];
        float s = 0.f, s2 = 0.f;
#pragma unroll
        for (int j = 0; j < 4; ++j) {
            ushort4 u = *(const ushort4*)(x + j * 256 + lane * 4);
            float a = b2f(u.x), b = b2f(u.y), c = b2f(u.z), d = b2f(u.w);
            v[j * 4 + 0] = a; v[j * 4 + 1] = b; v[j * 4 + 2] = c; v[j * 4 + 3] = d;
            s += a + b + c + d;
            s2 += a * a + b * b + c * c + d * d;
        }
#pragma unroll
        for (int o = 32; o > 0; o >>= 1) {
            s  += __shfl_xor(s, o, 64);
            s2 += __shfl_xor(s2, o, 64);
        }
        const float mu = s * (1.f / 1024.f);
        const float var = s2 * (1.f / 1024.f) - mu * mu;   // biased var (jnp.var)
        const float inv = rsqrtf(var + 1e-5f);
        const float* hrow = H + (size_t)row * 1024;
        float* orow = out + (size_t)row * 1024;
#pragma unroll
        for (int j = 0; j < 4; ++j) {
            const int c = j * 256 + lane * 4;
            float4 g = *(const float4*)(gamma + c);
            float4 bt = *(const float4*)(beta + c);
            float4 hr = *(const float4*)(hrow + c);
            float4 o;
            o.x = (v[j * 4 + 0] - mu) * inv * g.x + bt.x + hr.x;
            o.y = (v[j * 4 + 1] - mu) * inv * g.y + bt.y + hr.y;
            o.z = (v[j * 4 + 2] - mu) * inv * g.z + bt.z + hr.z;
            o.w = (v[j * 4 + 3] - mu) * inv * g.w + bt.w + hr.w;
            *(float4*)(orow + c) = o;
        }
    }
}

// ---------------------------------------------------------------------------
extern "C" void kernel_launch(void* const* d_in, const int* in_sizes, int n_in,
                              void* d_out, int out_size, void* d_ws, size_t ws_size,
                              hipStream_t stream) {
    const float* H     = (const float*)d_in[0];
    const float* Wqkv  = (const float*)d_in[1];
    const float* bqkv  = (const float*)d_in[2];
    const float* Wproj = (const float*)d_in[3];
    const float* bproj = (const float*)d_in[4];
    const float* gamma = (const float*)d_in[5];
    const float* beta  = (const float*)d_in[6];
    float* out = (float*)d_out;
    char* ws = (char*)d_ws;

    // ws layout (bytes); att aliases Hbf, out2 aliases qkv_bf (disjoint lifetimes)
    unsigned short* wq_bf = (unsigned short*)(ws);                 //   6,291,456
    unsigned short* wp_bf = (unsigned short*)(ws + 6291456);       //   2,097,152
    unsigned short* hbf   = (unsigned short*)(ws + 8388608);       //  67,108,864
    unsigned short* att   = hbf;
    unsigned short* qkvbf = (unsigned short*)(ws + 75497472);      // 201,326,592
    unsigned short* out2  = (unsigned short*)(ws + 75497472);      // bf16, 67MB
    float*          part  = (float*)(ws + 277889024);              //   8,519,680

    cvt_all<<<1984, 256, 0, stream>>>(H, Wqkv, Wproj, hbf, wq_bf, wp_bf);

    // GEMM1: M=32768 (mb=128), N=3072 -> grid 128*12 = 1536 (%8==0)
    gemm256<0><<<1536, 512, 0, stream>>>(hbf, wq_bf, bqkv, (void*)qkvbf,
                                         128, 3072, 1024);

    kv_partial<<<dim3(64, 8), 256, 0, stream>>>(qkvbf, part);

    apply_attn<<<dim3(128, 64), 256, 0, stream>>>(qkvbf, part, att);

    // GEMM2: 128^2 experiment: mb=256, nb=8 -> grid 2048 (%8==0); bf16 out
    gemm128<1><<<2048, 256, 0, stream>>>(att, wp_bf, bproj, (void*)out2,
                                         256, 1024, 1024);

    ln_residual<<<2048, 256, 0, stream>>>(out2, H, gamma, beta, out, 32768);
}

// Round 8
// 612.000 us; speedup vs baseline: 1.0358x; 1.0358x over previous
//
#include <hip/hip_runtime.h>

// LinearAttentionBlock: H(4,8192,1024) f32
// qkv = H@Wqkv^T + b; q,k = elu+1; per (b,h): kv = K^T V, k1 = sum k
// out = (q@kv)/(q.k1); scrambled reshape; @Wproj^T + b; LN; + residual
//
// R7: fix R6's wave-row bug (wr = wid>>2, NOT wid>>3 -- the latter is 0 for
// all 8 waves, leaving rows 128-255 unwritten). Supertile block order
// (GROUP_BM=4, bn-inner) + XCD chunking retained for the L2-locality test.

typedef __attribute__((ext_vector_type(4))) float f32x4;
typedef __attribute__((ext_vector_type(8))) short bf16x8;

__device__ __forceinline__ unsigned short f2b(float f) {
    unsigned u = __float_as_uint(f);
    u = (u + 0x7FFFu + ((u >> 16) & 1u)) >> 16;  // RNE
    return (unsigned short)u;
}
__device__ __forceinline__ float b2f(unsigned short h) {
    return __uint_as_float(((unsigned)h) << 16);
}

// async global->LDS, 16B per lane; LDS dest = wave-uniform base + lane*16.
__device__ __forceinline__ void glds16(const void* gp, void* lp) {
    __builtin_amdgcn_global_load_lds(
        (__attribute__((address_space(1))) void*)(unsigned long long)gp,
        (__attribute__((address_space(3))) void*)(unsigned int)(unsigned long long)lp,
        16, 0, 0);
}

// ---------------- fp32 -> bf16 conversion, all 3 inputs in one launch -----
__global__ __launch_bounds__(256) void cvt_all(const float* __restrict__ H,
                                               const float* __restrict__ Wq,
                                               const float* __restrict__ Wp,
                                               unsigned short* __restrict__ hbf,
                                               unsigned short* __restrict__ wqb,
                                               unsigned short* __restrict__ wpb) {
    const int blk = blockIdx.x;
    const float* src; unsigned short* dst; long n4; int b0, nb;
    if (blk < 1792)      { src = H;  dst = hbf; n4 = 8388608; b0 = 0;    nb = 1792; }
    else if (blk < 1920) { src = Wq; dst = wqb; n4 = 786432;  b0 = 1792; nb = 128; }
    else                 { src = Wp; dst = wpb; n4 = 262144;  b0 = 1920; nb = 64; }
    long i = (long)(blk - b0) * 256 + threadIdx.x;
    const long stride = (long)nb * 256;
    for (; i < n4; i += stride) {
        float4 v = ((const float4*)src)[i];
        ushort4 o;
        o.x = f2b(v.x); o.y = f2b(v.y); o.z = f2b(v.z); o.w = f2b(v.w);
        ((ushort4*)dst)[i] = o;
    }
}

// ---------------- bf16 MFMA GEMM, C = A @ B^T (+bias), 256^2 8-wave -------
// Block order: XCD chunk (bijective, grid%8==0) -> supertile decode:
// groups of 4 bm x all bn, bm fastest within each bn column. Per XCD the
// 4 hot A panels (2MB) + current B panel (512KB) stay L2-resident.
// MODE 0: v+=bias; col<2048 -> phi; store bf16.  MODE 1: v+=bias; store bf16.
template<int MODE>
__global__ __launch_bounds__(512) void gemm256(const unsigned short* __restrict__ A,
                                               const unsigned short* __restrict__ B,
                                               const float* __restrict__ bias,
                                               void* __restrict__ Cout,
                                               int mb, int N, int K) {
    __shared__ unsigned short lds[2][2][256][64];  // 128 KiB
    const int tid = threadIdx.x;
    const int wid = tid >> 6, lane = tid & 63;
    const int wr = wid >> 2, wc = wid & 3;       // 2M x 4N waves (wr in {0,1})
    const int lr = lane & 15, lq = lane >> 4;
    // XCD chunk transform then supertile decode (GROUP_BM=4, bn-inner)
    const int cpx = (int)gridDim.x >> 3;
    const int L = ((int)blockIdx.x & 7) * cpx + ((int)blockIdx.x >> 3);
    const int nbv = N >> 8;                      // N/256 tiles
    const int gsz = 4 * nbv;
    const int g = L / gsz, r = L % gsz;
    const int bn = r >> 2;
    const int bm = g * 4 + (r & 3);
    const size_t aRow0 = (size_t)bm * 256, bRow0 = (size_t)bn * 256;

    const int sr8 = lane >> 3;
    const int ssw = ((lane & 7) ^ sr8) * 8;      // pre-swizzled source col
    const unsigned short* aG = A + (aRow0 + (size_t)(wid * 8 + sr8)) * K + ssw;
    const unsigned short* bG = B + (bRow0 + (size_t)(wid * 8 + sr8)) * K + ssw;

    f32x4 acc[8][4] = {};
    const char* base = (const char*)&lds[0][0][0][0];

    auto stage = [&](int buf, int k0) {
#pragma unroll
        for (int j = 0; j < 8; ++j) {
            const unsigned short* g2 = (j < 4 ? aG : bG) + (size_t)(j & 3) * 64 * K + k0;
            glds16(g2, &lds[buf][j >> 2][(j & 3) * 64 + wid * 8][0]);
        }
    };
    auto ldA = [&](int cur, int mi, int ks) {
        int row = wr * 128 + mi * 16 + lr;
        int off = (cur * 2 + 0) * 32768 + row * 128 + ((((ks << 2) | lq) ^ (row & 7)) << 4);
        return *(const bf16x8*)(base + off);
    };
    auto ldB = [&](int cur, int ni, int ks) {
        int row = wc * 64 + ni * 16 + lr;
        int off = (cur * 2 + 1) * 32768 + row * 128 + ((((ks << 2) | lq) ^ (row & 7)) << 4);
        return *(const bf16x8*)(base + off);
    };

    const int nt = K >> 6;
    stage(0, 0);
    asm volatile("s_waitcnt vmcnt(0)" ::: "memory");
    __builtin_amdgcn_s_barrier();

    bf16x8 af[4][2], bfr[4][2];
    for (int t = 0; t < nt; ++t) {
        const int cur = t & 1;
        // ---- phase 0: read A-half(wr) mi0-3 + B ni0-1; stage t+1; MFMA Q(0,0)
#pragma unroll
        for (int mi = 0; mi < 4; ++mi) {
            af[mi][0] = ldA(cur, mi, 0); af[mi][1] = ldA(cur, mi, 1);
        }
#pragma unroll
        for (int ni = 0; ni < 2; ++ni) {
            bfr[ni][0] = ldB(cur, ni, 0); bfr[ni][1] = ldB(cur, ni, 1);
        }
        if (t + 1 < nt) stage(cur ^ 1, (t + 1) << 6);
        __builtin_amdgcn_s_barrier();
        __builtin_amdgcn_s_setprio(1);
#pragma unroll
        for (int mi = 0; mi < 4; ++mi)
#pragma unroll
            for (int ni = 0; ni < 2; ++ni)
#pragma unroll
                for (int ks = 0; ks < 2; ++ks)
                    acc[mi][ni] = __builtin_amdgcn_mfma_f32_16x16x32_bf16(
                        af[mi][ks], bfr[ni][ks], acc[mi][ni], 0, 0, 0);
        __builtin_amdgcn_s_setprio(0);
        __builtin_amdgcn_s_barrier();
        // ---- phase 1: read B ni2-3; MFMA Q(0,1)
#pragma unroll
        for (int ni = 2; ni < 4; ++ni) {
            bfr[ni][0] = ldB(cur, ni, 0); bfr[ni][1] = ldB(cur, ni, 1);
        }
        __builtin_amdgcn_s_barrier();
        __builtin_amdgcn_s_setprio(1);
#pragma unroll
        for (int mi = 0; mi < 4; ++mi)
#pragma unroll
            for (int ni = 2; ni < 4; ++ni)
#pragma unroll
                for (int ks = 0; ks < 2; ++ks)
                    acc[mi][ni] = __builtin_amdgcn_mfma_f32_16x16x32_bf16(
                        af[mi][ks], bfr[ni][ks], acc[mi][ni], 0, 0, 0);
        __builtin_amdgcn_s_setprio(0);
        __builtin_amdgcn_s_barrier();
        // ---- phase 2: read A-half mi4-7 (reuse af regs); MFMA Q(1,1)
#pragma unroll
        for (int mi = 0; mi < 4; ++mi) {
            af[mi][0] = ldA(cur, mi + 4, 0); af[mi][1] = ldA(cur, mi + 4, 1);
        }
        __builtin_amdgcn_s_barrier();
        __builtin_amdgcn_s_setprio(1);
#pragma unroll
        for (int mi = 0; mi < 4; ++mi)
#pragma unroll
            for (int ni = 2; ni < 4; ++ni)
#pragma unroll
                for (int ks = 0; ks < 2; ++ks)
                    acc[mi + 4][ni] = __builtin_amdgcn_mfma_f32_16x16x32_bf16(
                        af[mi][ks], bfr[ni][ks], acc[mi + 4][ni], 0, 0, 0);
        __builtin_amdgcn_s_setprio(0);
        __builtin_amdgcn_s_barrier();
        // ---- phase 3: MFMA Q(1,0) (no reads)
        __builtin_amdgcn_s_setprio(1);
#pragma unroll
        for (int mi = 0; mi < 4; ++mi)
#pragma unroll
            for (int ni = 0; ni < 2; ++ni)
#pragma unroll
                for (int ks = 0; ks < 2; ++ks)
                    acc[mi + 4][ni] = __builtin_amdgcn_mfma_f32_16x16x32_bf16(
                        af[mi][ks], bfr[ni][ks], acc[mi + 4][ni], 0, 0, 0);
        __builtin_amdgcn_s_setprio(0);
        // ---- tile boundary: next buffer landed; all reads of cur done
        asm volatile("s_waitcnt vmcnt(0)" ::: "memory");
        __builtin_amdgcn_s_barrier();
        __builtin_amdgcn_sched_barrier(0);
    }
    // epilogue: C/D layout col=lane&15, row=(lane>>4)*4+reg
#pragma unroll
    for (int mi = 0; mi < 8; ++mi) {
#pragma unroll
        for (int ni = 0; ni < 4; ++ni) {
            int col = (int)bRow0 + wc * 64 + ni * 16 + lr;
            float bv = bias[col];
#pragma unroll
            for (int r2 = 0; r2 < 4; ++r2) {
                size_t row = aRow0 + wr * 128 + mi * 16 + lq * 4 + r2;
                float v = acc[mi][ni][r2] + bv;
                if (MODE == 0) {
                    if (col < 2048) v = (v > 0.f) ? (v + 1.f) : __expf(v);  // elu+1
                }
                ((unsigned short*)Cout)[row * (size_t)N + col] = f2b(v);
            }
        }
    }
}

// ---------------- kv split-K partials: per (b,h,chunk of 1024 rows) -------
// part[(bh*8+chunk)] = [64x64 kv | 64 k1]  (4160 floats)
__global__ __launch_bounds__(256) void kv_partial(const unsigned short* __restrict__ qkv,
                                                  float* __restrict__ part) {
    const int bh = blockIdx.x, chunk = blockIdx.y;
    const int b = bh >> 4, h = bh & 15;
    __shared__ unsigned short kb[16][64];
    __shared__ unsigned short vb[16][64];
    const int tid = threadIdx.x;
    const int d0 = (tid >> 4) * 4, v0 = (tid & 15) * 4;
    float acc[4][4] = {};
    float k1a[4] = {0.f, 0.f, 0.f, 0.f};
    const size_t base = ((size_t)b * 8192 + (size_t)chunk * 1024) * 3072;
    const int nn = tid >> 4;          // staged row 0..15
    const int which = (tid >> 3) & 1; // 0: k, 1: v
    const int cg = tid & 7;           // 8-elem group
    const size_t loff = base + (size_t)nn * 3072 + (which ? 2048 : 1024) + h * 64 + cg * 8;

    for (int n0 = 0; n0 < 1024; n0 += 16) {
        uint4 val = *(const uint4*)(qkv + loff + (size_t)n0 * 3072);
        if (which) *(uint4*)(&vb[nn][cg * 8]) = val;
        else       *(uint4*)(&kb[nn][cg * 8]) = val;
        __syncthreads();
#pragma unroll 4
        for (int j = 0; j < 16; ++j) {
            ushort4 ku = *(const ushort4*)(&kb[j][d0]);
            ushort4 vu = *(const ushort4*)(&vb[j][v0]);
            float kd[4] = {b2f(ku.x), b2f(ku.y), b2f(ku.z), b2f(ku.w)};
            float vd[4] = {b2f(vu.x), b2f(vu.y), b2f(vu.z), b2f(vu.w)};
#pragma unroll
            for (int i = 0; i < 4; ++i)
#pragma unroll
                for (int jj = 0; jj < 4; ++jj)
                    acc[i][jj] += kd[i] * vd[jj];
            if ((tid & 15) == 0)
#pragma unroll
                for (int i = 0; i < 4; ++i) k1a[i] += kd[i];
        }
        __syncthreads();
    }
    float* dst = part + ((size_t)bh * 8 + chunk) * 4160;
#pragma unroll
    for (int i = 0; i < 4; ++i)
#pragma unroll
        for (int jj = 0; jj < 4; ++jj)
            dst[(d0 + i) * 64 + v0 + jj] = acc[i][jj];
    if ((tid & 15) == 0)
#pragma unroll
        for (int i = 0; i < 4; ++i) dst[4096 + d0 + i] = k1a[i];
}

// ---------------- apply: reduce partials + out=(q@kv)/max(q.k1,1e-6) ------
// block: 64 n-rows; thread t: row r=t>>2, col quarter qt=t&3 (16 outputs)
__global__ __launch_bounds__(256) void apply_attn(const unsigned short* __restrict__ qkv,
                                                  const float* __restrict__ part,
                                                  unsigned short* __restrict__ att) {
    const int nblk = blockIdx.x;
    const int bh = blockIdx.y;
    const int b = bh >> 4, h = bh & 15;
    __shared__ float kvs[64][64];
    __shared__ float k1s[64];
    const float* src = part + (size_t)bh * 8 * 4160;
    for (int i = threadIdx.x; i < 4096; i += 256) {
        float s = 0.f;
#pragma unroll
        for (int c = 0; c < 8; ++c) s += src[c * 4160 + i];
        kvs[i >> 6][i & 63] = s;
    }
    if (threadIdx.x < 64) {
        float s = 0.f;
#pragma unroll
        for (int c = 0; c < 8; ++c) s += src[c * 4160 + 4096 + threadIdx.x];
        k1s[threadIdx.x] = s;
    }
    __syncthreads();
    const int t = threadIdx.x;
    const int r = t >> 2, qt = t & 3;
    const int n = nblk * 64 + r;
    const unsigned short* qrow = qkv + ((size_t)b * 8192 + n) * 3072 + h * 64;
    float acc[16] = {};
    float qk1 = 0.f;
    for (int dc = 0; dc < 64; dc += 8) {
        uint4 qu = *(const uint4*)(qrow + dc);
        unsigned qw[4] = {qu.x, qu.y, qu.z, qu.w};
#pragma unroll
        for (int jj = 0; jj < 8; ++jj) {
            float qd = (jj & 1) ? __uint_as_float(qw[jj >> 1] & 0xFFFF0000u)
                                : __uint_as_float(qw[jj >> 1] << 16);
            int d = dc + jj;
            qk1 += qd * k1s[d];
            const float4* kr = (const float4*)(&kvs[d][qt * 16]);  // 4-addr broadcast
            float4 c0 = kr[0], c1 = kr[1], c2 = kr[2], c3 = kr[3];
            acc[0]  += qd * c0.x; acc[1]  += qd * c0.y; acc[2]  += qd * c0.z; acc[3]  += qd * c0.w;
            acc[4]  += qd * c1.x; acc[5]  += qd * c1.y; acc[6]  += qd * c1.z; acc[7]  += qd * c1.w;
            acc[8]  += qd * c2.x; acc[9]  += qd * c2.y; acc[10] += qd * c2.z; acc[11] += qd * c2.w;
            acc[12] += qd * c3.x; acc[13] += qd * c3.y; acc[14] += qd * c3.z; acc[15] += qd * c3.w;
        }
    }
    float rinv = 1.f / fmaxf(qk1, 1e-6f);
    union { unsigned short us[16]; uint4 u4[2]; } ob;
#pragma unroll
    for (int j = 0; j < 16; ++j) ob.us[j] = f2b(acc[j] * rinv);
    // bug-faithful reshape: (h,n,dd) -> row h*512 + n/16, col (n%16)*64 + dd
    unsigned short* dst = att + (((size_t)b * 8192) + h * 512 + (n >> 4)) * 1024
                              + (n & 15) * 64 + qt * 16;
    *(uint4*)dst = ob.u4[0];
    *(uint4*)(dst + 8) = ob.u4[1];
}

// ---------------- LayerNorm + residual, 1 wave per row, barrier-free ------
__global__ __launch_bounds__(256) void ln_residual(const unsigned short* __restrict__ X,
                                                   const float* __restrict__ H,
                                                   const float* __restrict__ gamma,
                                                   const float* __restrict__ beta,
                                                   float* __restrict__ out,
                                                   int nrows) {
    const int lane = threadIdx.x & 63;
    int row = blockIdx.x * 4 + (threadIdx.x >> 6);
    const int rstride = gridDim.x * 4;
    for (; row < nrows; row += rstride) {
        const unsigned short* x = X + (size_t)row * 1024;
        float v[16];
        float s = 0.f, s2 = 0.f;
#pragma unroll
        for (int j = 0; j < 4; ++j) {
            ushort4 u = *(const ushort4*)(x + j * 256 + lane * 4);
            float a = b2f(u.x), b = b2f(u.y), c = b2f(u.z), d = b2f(u.w);
            v[j * 4 + 0] = a; v[j * 4 + 1] = b; v[j * 4 + 2] = c; v[j * 4 + 3] = d;
            s += a + b + c + d;
            s2 += a * a + b * b + c * c + d * d;
        }
#pragma unroll
        for (int o = 32; o > 0; o >>= 1) {
            s  += __shfl_xor(s, o, 64);
            s2 += __shfl_xor(s2, o, 64);
        }
        const float mu = s * (1.f / 1024.f);
        const float var = s2 * (1.f / 1024.f) - mu * mu;   // biased var (jnp.var)
        const float inv = rsqrtf(var + 1e-5f);
        const float* hrow = H + (size_t)row * 1024;
        float* orow = out + (size_t)row * 1024;
#pragma unroll
        for (int j = 0; j < 4; ++j) {
            const int c = j * 256 + lane * 4;
            float4 g = *(const float4*)(gamma + c);
            float4 bt = *(const float4*)(beta + c);
            float4 hr = *(const float4*)(hrow + c);
            float4 o;
            o.x = (v[j * 4 + 0] - mu) * inv * g.x + bt.x + hr.x;
            o.y = (v[j * 4 + 1] - mu) * inv * g.y + bt.y + hr.y;
            o.z = (v[j * 4 + 2] - mu) * inv * g.z + bt.z + hr.z;
            o.w = (v[j * 4 + 3] - mu) * inv * g.w + bt.w + hr.w;
            *(float4*)(orow + c) = o;
        }
    }
}

// ---------------------------------------------------------------------------
extern "C" void kernel_launch(void* const* d_in, const int* in_sizes, int n_in,
                              void* d_out, int out_size, void* d_ws, size_t ws_size,
                              hipStream_t stream) {
    const float* H     = (const float*)d_in[0];
    const float* Wqkv  = (const float*)d_in[1];
    const float* bqkv  = (const float*)d_in[2];
    const float* Wproj = (const float*)d_in[3];
    const float* bproj = (const float*)d_in[4];
    const float* gamma = (const float*)d_in[5];
    const float* beta  = (const float*)d_in[6];
    float* out = (float*)d_out;
    char* ws = (char*)d_ws;

    // ws layout (bytes); att aliases Hbf, out2 aliases qkv_bf (disjoint lifetimes)
    unsigned short* wq_bf = (unsigned short*)(ws);                 //   6,291,456
    unsigned short* wp_bf = (unsigned short*)(ws + 6291456);       //   2,097,152
    unsigned short* hbf   = (unsigned short*)(ws + 8388608);       //  67,108,864
    unsigned short* att   = hbf;
    unsigned short* qkvbf = (unsigned short*)(ws + 75497472);      // 201,326,592
    unsigned short* out2  = (unsigned short*)(ws + 75497472);      // bf16, 67MB
    float*          part  = (float*)(ws + 277889024);              //   8,519,680

    cvt_all<<<1984, 256, 0, stream>>>(H, Wqkv, Wproj, hbf, wq_bf, wp_bf);

    // GEMM1: M=32768 (mb=128), N=3072 -> grid 128*12 = 1536 (%8==0)
    gemm256<0><<<1536, 512, 0, stream>>>(hbf, wq_bf, bqkv, (void*)qkvbf,
                                         128, 3072, 1024);

    kv_partial<<<dim3(64, 8), 256, 0, stream>>>(qkvbf, part);

    apply_attn<<<dim3(128, 64), 256, 0, stream>>>(qkvbf, part, att);

    // GEMM2: M=32768 (mb=128), N=1024 -> grid 128*4 = 512 (%8==0); bf16 out
    gemm256<1><<<512, 512, 0, stream>>>(att, wp_bf, bproj, (void*)out2,
                                        128, 1024, 1024);

    ln_residual<<<2048, 256, 0, stream>>>(out2, H, gamma, beta, out, 32768);
}

// Round 9
// 564.028 us; speedup vs baseline: 1.1239x; 1.0851x over previous
//
#include <hip/hip_runtime.h>

// LinearAttentionBlock: H(4,8192,1024) f32
// qkv = H@Wqkv^T + b; q,k = elu+1; per (b,h): kv = K^T V, k1 = sum k
// out = (q@kv)/(q.k1); scrambled reshape; @Wproj^T + b; LN; + residual
//
// R8: apply_attn -> MFMA (q rows as A, kv^T bf16 as B via swizzled LDS);
// kv_partial now stores transposed partials; new kv_finish reduces to
// bf16 kv^T + f32 k1. GEMM1/GEMM2 unchanged (813 TF = structural plateau;
// R7 falsified the BW-bound model: FETCH 405->165MB, dur flat).

typedef __attribute__((ext_vector_type(4))) float f32x4;
typedef __attribute__((ext_vector_type(8))) short bf16x8;

__device__ __forceinline__ unsigned short f2b(float f) {
    unsigned u = __float_as_uint(f);
    u = (u + 0x7FFFu + ((u >> 16) & 1u)) >> 16;  // RNE
    return (unsigned short)u;
}
__device__ __forceinline__ float b2f(unsigned short h) {
    return __uint_as_float(((unsigned)h) << 16);
}

// async global->LDS, 16B per lane; LDS dest = wave-uniform base + lane*16.
__device__ __forceinline__ void glds16(const void* gp, void* lp) {
    __builtin_amdgcn_global_load_lds(
        (__attribute__((address_space(1))) void*)(unsigned long long)gp,
        (__attribute__((address_space(3))) void*)(unsigned int)(unsigned long long)lp,
        16, 0, 0);
}

// ---------------- fp32 -> bf16 conversion, all 3 inputs in one launch -----
__global__ __launch_bounds__(256) void cvt_all(const float* __restrict__ H,
                                               const float* __restrict__ Wq,
                                               const float* __restrict__ Wp,
                                               unsigned short* __restrict__ hbf,
                                               unsigned short* __restrict__ wqb,
                                               unsigned short* __restrict__ wpb) {
    const int blk = blockIdx.x;
    const float* src; unsigned short* dst; long n4; int b0, nb;
    if (blk < 1792)      { src = H;  dst = hbf; n4 = 8388608; b0 = 0;    nb = 1792; }
    else if (blk < 1920) { src = Wq; dst = wqb; n4 = 786432;  b0 = 1792; nb = 128; }
    else                 { src = Wp; dst = wpb; n4 = 262144;  b0 = 1920; nb = 64; }
    long i = (long)(blk - b0) * 256 + threadIdx.x;
    const long stride = (long)nb * 256;
    for (; i < n4; i += stride) {
        float4 v = ((const float4*)src)[i];
        ushort4 o;
        o.x = f2b(v.x); o.y = f2b(v.y); o.z = f2b(v.z); o.w = f2b(v.w);
        ((ushort4*)dst)[i] = o;
    }
}

// ---------------- bf16 MFMA GEMM, C = A @ B^T (+bias), 256^2 8-wave -------
// XCD chunk -> supertile (GROUP_BM=4, bn-inner): per-XCD A panels L2-hot.
template<int MODE>
__global__ __launch_bounds__(512) void gemm256(const unsigned short* __restrict__ A,
                                               const unsigned short* __restrict__ B,
                                               const float* __restrict__ bias,
                                               void* __restrict__ Cout,
                                               int mb, int N, int K) {
    __shared__ unsigned short lds[2][2][256][64];  // 128 KiB
    const int tid = threadIdx.x;
    const int wid = tid >> 6, lane = tid & 63;
    const int wr = wid >> 2, wc = wid & 3;       // 2M x 4N waves
    const int lr = lane & 15, lq = lane >> 4;
    const int cpx = (int)gridDim.x >> 3;
    const int L = ((int)blockIdx.x & 7) * cpx + ((int)blockIdx.x >> 3);
    const int nbv = N >> 8;
    const int gsz = 4 * nbv;
    const int g = L / gsz, r = L % gsz;
    const int bn = r >> 2;
    const int bm = g * 4 + (r & 3);
    const size_t aRow0 = (size_t)bm * 256, bRow0 = (size_t)bn * 256;

    const int sr8 = lane >> 3;
    const int ssw = ((lane & 7) ^ sr8) * 8;      // pre-swizzled source col
    const unsigned short* aG = A + (aRow0 + (size_t)(wid * 8 + sr8)) * K + ssw;
    const unsigned short* bG = B + (bRow0 + (size_t)(wid * 8 + sr8)) * K + ssw;

    f32x4 acc[8][4] = {};
    const char* base = (const char*)&lds[0][0][0][0];

    auto stage = [&](int buf, int k0) {
#pragma unroll
        for (int j = 0; j < 8; ++j) {
            const unsigned short* g2 = (j < 4 ? aG : bG) + (size_t)(j & 3) * 64 * K + k0;
            glds16(g2, &lds[buf][j >> 2][(j & 3) * 64 + wid * 8][0]);
        }
    };
    auto ldA = [&](int cur, int mi, int ks) {
        int row = wr * 128 + mi * 16 + lr;
        int off = (cur * 2 + 0) * 32768 + row * 128 + ((((ks << 2) | lq) ^ (row & 7)) << 4);
        return *(const bf16x8*)(base + off);
    };
    auto ldB = [&](int cur, int ni, int ks) {
        int row = wc * 64 + ni * 16 + lr;
        int off = (cur * 2 + 1) * 32768 + row * 128 + ((((ks << 2) | lq) ^ (row & 7)) << 4);
        return *(const bf16x8*)(base + off);
    };

    const int nt = K >> 6;
    stage(0, 0);
    asm volatile("s_waitcnt vmcnt(0)" ::: "memory");
    __builtin_amdgcn_s_barrier();

    bf16x8 af[4][2], bfr[4][2];
    for (int t = 0; t < nt; ++t) {
        const int cur = t & 1;
#pragma unroll
        for (int mi = 0; mi < 4; ++mi) {
            af[mi][0] = ldA(cur, mi, 0); af[mi][1] = ldA(cur, mi, 1);
        }
#pragma unroll
        for (int ni = 0; ni < 2; ++ni) {
            bfr[ni][0] = ldB(cur, ni, 0); bfr[ni][1] = ldB(cur, ni, 1);
        }
        if (t + 1 < nt) stage(cur ^ 1, (t + 1) << 6);
        __builtin_amdgcn_s_barrier();
        __builtin_amdgcn_s_setprio(1);
#pragma unroll
        for (int mi = 0; mi < 4; ++mi)
#pragma unroll
            for (int ni = 0; ni < 2; ++ni)
#pragma unroll
                for (int ks = 0; ks < 2; ++ks)
                    acc[mi][ni] = __builtin_amdgcn_mfma_f32_16x16x32_bf16(
                        af[mi][ks], bfr[ni][ks], acc[mi][ni], 0, 0, 0);
        __builtin_amdgcn_s_setprio(0);
        __builtin_amdgcn_s_barrier();
#pragma unroll
        for (int ni = 2; ni < 4; ++ni) {
            bfr[ni][0] = ldB(cur, ni, 0); bfr[ni][1] = ldB(cur, ni, 1);
        }
        __builtin_amdgcn_s_barrier();
        __builtin_amdgcn_s_setprio(1);
#pragma unroll
        for (int mi = 0; mi < 4; ++mi)
#pragma unroll
            for (int ni = 2; ni < 4; ++ni)
#pragma unroll
                for (int ks = 0; ks < 2; ++ks)
                    acc[mi][ni] = __builtin_amdgcn_mfma_f32_16x16x32_bf16(
                        af[mi][ks], bfr[ni][ks], acc[mi][ni], 0, 0, 0);
        __builtin_amdgcn_s_setprio(0);
        __builtin_amdgcn_s_barrier();
#pragma unroll
        for (int mi = 0; mi < 4; ++mi) {
            af[mi][0] = ldA(cur, mi + 4, 0); af[mi][1] = ldA(cur, mi + 4, 1);
        }
        __builtin_amdgcn_s_barrier();
        __builtin_amdgcn_s_setprio(1);
#pragma unroll
        for (int mi = 0; mi < 4; ++mi)
#pragma unroll
            for (int ni = 2; ni < 4; ++ni)
#pragma unroll
                for (int ks = 0; ks < 2; ++ks)
                    acc[mi + 4][ni] = __builtin_amdgcn_mfma_f32_16x16x32_bf16(
                        af[mi][ks], bfr[ni][ks], acc[mi + 4][ni], 0, 0, 0);
        __builtin_amdgcn_s_setprio(0);
        __builtin_amdgcn_s_barrier();
        __builtin_amdgcn_s_setprio(1);
#pragma unroll
        for (int mi = 0; mi < 4; ++mi)
#pragma unroll
            for (int ni = 0; ni < 2; ++ni)
#pragma unroll
                for (int ks = 0; ks < 2; ++ks)
                    acc[mi + 4][ni] = __builtin_amdgcn_mfma_f32_16x16x32_bf16(
                        af[mi][ks], bfr[ni][ks], acc[mi + 4][ni], 0, 0, 0);
        __builtin_amdgcn_s_setprio(0);
        asm volatile("s_waitcnt vmcnt(0)" ::: "memory");
        __builtin_amdgcn_s_barrier();
        __builtin_amdgcn_sched_barrier(0);
    }
#pragma unroll
    for (int mi = 0; mi < 8; ++mi) {
#pragma unroll
        for (int ni = 0; ni < 4; ++ni) {
            int col = (int)bRow0 + wc * 64 + ni * 16 + lr;
            float bv = bias[col];
#pragma unroll
            for (int r2 = 0; r2 < 4; ++r2) {
                size_t row = aRow0 + wr * 128 + mi * 16 + lq * 4 + r2;
                float v = acc[mi][ni][r2] + bv;
                if (MODE == 0) {
                    if (col < 2048) v = (v > 0.f) ? (v + 1.f) : __expf(v);  // elu+1
                }
                ((unsigned short*)Cout)[row * (size_t)N + col] = f2b(v);
            }
        }
    }
}

// ---------------- kv split-K partials: per (b,h,chunk of 1024 rows) -------
// part[(bh*8+chunk)] = [64x64 kv^T (v-major: [v][d]) | 64 k1]  (4160 floats)
__global__ __launch_bounds__(256) void kv_partial(const unsigned short* __restrict__ qkv,
                                                  float* __restrict__ part) {
    const int bh = blockIdx.x, chunk = blockIdx.y;
    const int b = bh >> 4, h = bh & 15;
    __shared__ unsigned short kb[16][64];
    __shared__ unsigned short vb[16][64];
    const int tid = threadIdx.x;
    const int d0 = (tid >> 4) * 4, v0 = (tid & 15) * 4;
    float acc[4][4] = {};
    float k1a[4] = {0.f, 0.f, 0.f, 0.f};
    const size_t base = ((size_t)b * 8192 + (size_t)chunk * 1024) * 3072;
    const int nn = tid >> 4;
    const int which = (tid >> 3) & 1;
    const int cg = tid & 7;
    const size_t loff = base + (size_t)nn * 3072 + (which ? 2048 : 1024) + h * 64 + cg * 8;

    for (int n0 = 0; n0 < 1024; n0 += 16) {
        uint4 val = *(const uint4*)(qkv + loff + (size_t)n0 * 3072);
        if (which) *(uint4*)(&vb[nn][cg * 8]) = val;
        else       *(uint4*)(&kb[nn][cg * 8]) = val;
        __syncthreads();
#pragma unroll 4
        for (int j = 0; j < 16; ++j) {
            ushort4 ku = *(const ushort4*)(&kb[j][d0]);
            ushort4 vu = *(const ushort4*)(&vb[j][v0]);
            float kd[4] = {b2f(ku.x), b2f(ku.y), b2f(ku.z), b2f(ku.w)};
            float vd[4] = {b2f(vu.x), b2f(vu.y), b2f(vu.z), b2f(vu.w)};
#pragma unroll
            for (int i = 0; i < 4; ++i)
#pragma unroll
                for (int jj = 0; jj < 4; ++jj)
                    acc[i][jj] += kd[i] * vd[jj];
            if ((tid & 15) == 0)
#pragma unroll
                for (int i = 0; i < 4; ++i) k1a[i] += kd[i];
        }
        __syncthreads();
    }
    float* dst = part + ((size_t)bh * 8 + chunk) * 4160;
#pragma unroll
    for (int i = 0; i < 4; ++i)
#pragma unroll
        for (int jj = 0; jj < 4; ++jj)
            dst[(v0 + jj) * 64 + d0 + i] = acc[i][jj];   // TRANSPOSED: [v][d]
    if ((tid & 15) == 0)
#pragma unroll
        for (int i = 0; i < 4; ++i) dst[4096 + d0 + i] = k1a[i];
}

// ---------------- kv_finish: reduce 8 partials -> bf16 kv^T + f32 k1 ------
__global__ __launch_bounds__(256) void kv_finish(const float* __restrict__ part,
                                                 unsigned short* __restrict__ kvbf,
                                                 float* __restrict__ k1f) {
    const int bh = blockIdx.x;
    const float* src = part + (size_t)bh * 8 * 4160;
    for (int i = threadIdx.x; i < 4096; i += 256) {
        float s = 0.f;
#pragma unroll
        for (int c = 0; c < 8; ++c) s += src[c * 4160 + i];
        kvbf[(size_t)bh * 4096 + i] = f2b(s);
    }
    if (threadIdx.x < 64) {
        float s = 0.f;
#pragma unroll
        for (int c = 0; c < 8; ++c) s += src[c * 4160 + 4096 + threadIdx.x];
        k1f[bh * 64 + threadIdx.x] = s;
    }
}

// ---------------- apply (MFMA): out = (q@kv)/max(q.k1,1e-6), scrambled ----
// grid (nblk=128, bh=64), 256 thr = 4 waves; block = 64 n-rows.
// A-frags: q direct from global. B-frags: kv^T bf16 in XOR-swizzled LDS.
__global__ __launch_bounds__(256) void apply_attn(const unsigned short* __restrict__ qkv,
                                                  const unsigned short* __restrict__ kvbf,
                                                  const float* __restrict__ k1f,
                                                  unsigned short* __restrict__ att) {
    const int nblk = blockIdx.x;
    const int bh = blockIdx.y;
    const int b = bh >> 4, h = bh & 15;
    __shared__ unsigned short kvs[64][64];   // [v][d], slot-swizzled
    __shared__ float k1s[64];
    __shared__ float qk1s[64];
    const int tid = threadIdx.x;
    // stage kv^T: thread t -> v = t>>3 (+32), slot s = t&7; phys slot = s^(v&7)
    {
        const int v = tid >> 3, s = tid & 7;
        const uint4* srcv = (const uint4*)(kvbf + (size_t)bh * 4096);
#pragma unroll
        for (int half = 0; half < 2; ++half) {
            int vv = v + half * 32;
            uint4 val = srcv[vv * 8 + s];
            *(uint4*)(&kvs[vv][(s ^ (vv & 7)) * 8]) = val;
        }
        if (tid < 64) k1s[tid] = k1f[bh * 64 + tid];
    }
    __syncthreads();
    const int n0 = nblk * 64;
    const size_t qbase = ((size_t)b * 8192 + n0) * 3072 + h * 64;
    // qk1 phase: thread t: row t>>2, d-quarter (t&3)*16
    {
        const int row = tid >> 2, dq = (tid & 3) * 16;
        const unsigned short* qp = qkv + qbase + (size_t)row * 3072 + dq;
        float s = 0.f;
#pragma unroll
        for (int g2 = 0; g2 < 2; ++g2) {
            ushort4 u0 = *(const ushort4*)(qp + g2 * 8);
            ushort4 u1 = *(const ushort4*)(qp + g2 * 8 + 4);
            const float* kp = &k1s[dq + g2 * 8];
            s += b2f(u0.x) * kp[0] + b2f(u0.y) * kp[1] + b2f(u0.z) * kp[2] + b2f(u0.w) * kp[3]
               + b2f(u1.x) * kp[4] + b2f(u1.y) * kp[5] + b2f(u1.z) * kp[6] + b2f(u1.w) * kp[7];
        }
        s += __shfl_xor(s, 1, 64);
        s += __shfl_xor(s, 2, 64);
        if ((tid & 3) == 0) qk1s[row] = s;
    }
    __syncthreads();
    // MFMA: wave w owns rows w*16..+16; ni=0..3 covers v=0..63; ks=0..1 (d)
    const int w = tid >> 6, lane = tid & 63;
    const int lr = lane & 15, lq = lane >> 4;
    bf16x8 af[2];
#pragma unroll
    for (int ks = 0; ks < 2; ++ks)
        af[ks] = *(const bf16x8*)(qkv + qbase + (size_t)(w * 16 + lr) * 3072 + ks * 32 + lq * 8);
    f32x4 acc[4] = {};
#pragma unroll
    for (int ni = 0; ni < 4; ++ni)
#pragma unroll
        for (int ks = 0; ks < 2; ++ks) {
            int v = ni * 16 + lr;
            bf16x8 bf = *(const bf16x8*)(&kvs[v][(((ks << 2) | lq) ^ (v & 7)) * 8]);
            acc[ni] = __builtin_amdgcn_mfma_f32_16x16x32_bf16(af[ks], bf, acc[ni], 0, 0, 0);
        }
    // epilogue: C row = lq*4+r (n within 16), col = v = ni*16+lr
    // n = n0 + w*16 + lq*4 + r; dst row = h*512 + nblk*4 + w (const per wave)
    unsigned short* dstrow = att + (((size_t)b * 8192) + h * 512 + nblk * 4 + w) * 1024;
#pragma unroll
    for (int r = 0; r < 4; ++r) {
        float rinv = 1.f / fmaxf(qk1s[w * 16 + lq * 4 + r], 1e-6f);
#pragma unroll
        for (int ni = 0; ni < 4; ++ni)
            dstrow[(lq * 4 + r) * 64 + ni * 16 + lr] = f2b(acc[ni][r] * rinv);
    }
}

// ---------------- LayerNorm + residual, 1 wave per row, barrier-free ------
__global__ __launch_bounds__(256) void ln_residual(const unsigned short* __restrict__ X,
                                                   const float* __restrict__ H,
                                                   const float* __restrict__ gamma,
                                                   const float* __restrict__ beta,
                                                   float* __restrict__ out,
                                                   int nrows) {
    const int lane = threadIdx.x & 63;
    int row = blockIdx.x * 4 + (threadIdx.x >> 6);
    const int rstride = gridDim.x * 4;
    for (; row < nrows; row += rstride) {
        const unsigned short* x = X + (size_t)row * 1024;
        float v[16];
        float s = 0.f, s2 = 0.f;
#pragma unroll
        for (int j = 0; j < 4; ++j) {
            ushort4 u = *(const ushort4*)(x + j * 256 + lane * 4);
            float a = b2f(u.x), b = b2f(u.y), c = b2f(u.z), d = b2f(u.w);
            v[j * 4 + 0] = a; v[j * 4 + 1] = b; v[j * 4 + 2] = c; v[j * 4 + 3] = d;
            s += a + b + c + d;
            s2 += a * a + b * b + c * c + d * d;
        }
#pragma unroll
        for (int o = 32; o > 0; o >>= 1) {
            s  += __shfl_xor(s, o, 64);
            s2 += __shfl_xor(s2, o, 64);
        }
        const float mu = s * (1.f / 1024.f);
        const float var = s2 * (1.f / 1024.f) - mu * mu;   // biased var (jnp.var)
        const float inv = rsqrtf(var + 1e-5f);
        const float* hrow = H + (size_t)row * 1024;
        float* orow = out + (size_t)row * 1024;
#pragma unroll
        for (int j = 0; j < 4; ++j) {
            const int c = j * 256 + lane * 4;
            float4 g = *(const float4*)(gamma + c);
            float4 bt = *(const float4*)(beta + c);
            float4 hr = *(const float4*)(hrow + c);
            float4 o;
            o.x = (v[j * 4 + 0] - mu) * inv * g.x + bt.x + hr.x;
            o.y = (v[j * 4 + 1] - mu) * inv * g.y + bt.y + hr.y;
            o.z = (v[j * 4 + 2] - mu) * inv * g.z + bt.z + hr.z;
            o.w = (v[j * 4 + 3] - mu) * inv * g.w + bt.w + hr.w;
            *(float4*)(orow + c) = o;
        }
    }
}

// ---------------------------------------------------------------------------
extern "C" void kernel_launch(void* const* d_in, const int* in_sizes, int n_in,
                              void* d_out, int out_size, void* d_ws, size_t ws_size,
                              hipStream_t stream) {
    const float* H     = (const float*)d_in[0];
    const float* Wqkv  = (const float*)d_in[1];
    const float* bqkv  = (const float*)d_in[2];
    const float* Wproj = (const float*)d_in[3];
    const float* bproj = (const float*)d_in[4];
    const float* gamma = (const float*)d_in[5];
    const float* beta  = (const float*)d_in[6];
    float* out = (float*)d_out;
    char* ws = (char*)d_ws;

    // ws layout (bytes); att aliases Hbf, out2 aliases qkvbf (disjoint lifetimes)
    unsigned short* wq_bf = (unsigned short*)(ws);                 //   6,291,456
    unsigned short* wp_bf = (unsigned short*)(ws + 6291456);       //   2,097,152
    unsigned short* hbf   = (unsigned short*)(ws + 8388608);       //  67,108,864
    unsigned short* att   = hbf;
    unsigned short* qkvbf = (unsigned short*)(ws + 75497472);      // 201,326,592
    unsigned short* out2  = (unsigned short*)(ws + 75497472);      // bf16, 67MB
    unsigned short* kvbf  = (unsigned short*)(ws + 276824064);     //     524,288
    float*          k1f   = (float*)(ws + 277348352);              //      16,384
    float*          part  = (float*)(ws + 277889024);              //   8,519,680

    cvt_all<<<1984, 256, 0, stream>>>(H, Wqkv, Wproj, hbf, wq_bf, wp_bf);

    // GEMM1: M=32768 (mb=128), N=3072 -> grid 128*12 = 1536 (%8==0)
    gemm256<0><<<1536, 512, 0, stream>>>(hbf, wq_bf, bqkv, (void*)qkvbf,
                                         128, 3072, 1024);

    kv_partial<<<dim3(64, 8), 256, 0, stream>>>(qkvbf, part);
    kv_finish<<<64, 256, 0, stream>>>(part, kvbf, k1f);

    apply_attn<<<dim3(128, 64), 256, 0, stream>>>(qkvbf, kvbf, k1f, att);

    // GEMM2: M=32768 (mb=128), N=1024 -> grid 128*4 = 512 (%8==0); bf16 out
    gemm256<1><<<512, 512, 0, stream>>>(att, wp_bf, bproj, (void*)out2,
                                        128, 1024, 1024);

    ln_residual<<<2048, 256, 0, stream>>>(out2, H, gamma, beta, out, 32768);
}